// Round 4
// baseline (282.746 us; speedup 1.0000x reference)
//
#include <hip/hip_runtime.h>
#include <hip/hip_bf16.h>
#include <math.h>

#define BB 4
#define NTOK 1024
#define DIMD 512
#define HH 8
#define DH 64
#define INNER 512
#define BH (BB*HH)          // 32
#define ROWS (BB*NTOK)      // 4096
#define SCALE 0.125f
#define INV_TEMP 10.0f

typedef __bf16 bf16_t;
using bf16x4 = __attribute__((ext_vector_type(4))) __bf16;
using bf16x8 = __attribute__((ext_vector_type(8))) __bf16;
using f32x4  = __attribute__((ext_vector_type(4))) float;

// XOR swizzle (element units, bf16): flips elem bits 3-5 by row -> spreads a
// b128 read across banks for 128B-row tiles; bijective within 64-el rows. [G4]
__device__ __forceinline__ int swz(int row, int e) { return e ^ ((row & 7) << 3); }

// Async global->LDS 16B: LDS dest is wave-uniform base + lane*16 (linear).
// Swizzled layouts are achieved by pre-swizzling the SOURCE address (m173).
__device__ __forceinline__ void gload_lds16(const bf16_t* g, bf16_t* l)
{
    __builtin_amdgcn_global_load_lds(
        (const __attribute__((address_space(1))) void*)g,
        (__attribute__((address_space(3))) void*)l, 16, 0, 0);
}

// ---------------------------------------------------------------------------
// Shared MFMA GEMM core (qkv_gemm / out_gemm): C[TM,TN] += A[TM,K]*B[TN,K]^T
// Ping-pong double-buffer, ONE barrier per K-step: stage(k+1) issues before
// compute(k); the compiler's vmcnt/lgkm drain at __syncthreads gives safety.
//   A frag (lane l): A[m = l&15][k = (l>>4)*8 + j]
//   C/D (lane l, reg r): row = (l>>4)*4 + r, col = l&15   [m89/m91 verified]
// As sized 2*TM*32, Bs sized 2*TN*32.
// ---------------------------------------------------------------------------
template<int TM, int TN, int MT, int NT>
__device__ __forceinline__ void gemm_core(
    const bf16_t* __restrict__ A, int ldA,
    const bf16_t* __restrict__ B, int ldB, int K,
    bf16_t* As, bf16_t* Bs, f32x4 (&acc)[MT][NT])
{
    const int t = threadIdx.x;
    const int w = t >> 6, l = t & 63;
    constexpr int WGN = TN / (NT * 16);
    const int wm = w / WGN, wn = w % WGN;
    const int lrow = l & 15, lk = (l >> 4) * 8;
    constexpr int ASZ = TM * 32, BSZ = TN * 32;

    auto stage = [&](int k0, int buf) {
        #pragma unroll
        for (int it = 0; it < TM / 64; ++it)
            gload_lds16(&A[(size_t)((t >> 2) + it * 64) * ldA + k0 + (t & 3) * 8],
                        As + buf * ASZ + ((size_t)it * 256 + w * 64) * 8);
        #pragma unroll
        for (int it = 0; it < TN / 64; ++it)
            gload_lds16(&B[(size_t)((t >> 2) + it * 64) * ldB + k0 + (t & 3) * 8],
                        Bs + buf * BSZ + ((size_t)it * 256 + w * 64) * 8);
    };

    stage(0, 0);
    __syncthreads();
    for (int k0 = 0; k0 < K; k0 += 32) {
        const int cur = (k0 >> 5) & 1;
        if (k0 + 32 < K) stage(k0 + 32, cur ^ 1);
        const bf16_t* Ac = As + cur * ASZ;
        const bf16_t* Bc = Bs + cur * BSZ;
        bf16x8 af[MT], bf[NT];
        #pragma unroll
        for (int mt = 0; mt < MT; ++mt)
            af[mt] = *(const bf16x8*)&Ac[(wm * MT * 16 + mt * 16 + lrow) * 32 + lk];
        #pragma unroll
        for (int nt = 0; nt < NT; ++nt)
            bf[nt] = *(const bf16x8*)&Bc[(wn * NT * 16 + nt * 16 + lrow) * 32 + lk];
        #pragma unroll
        for (int mt = 0; mt < MT; ++mt)
            #pragma unroll
            for (int nt = 0; nt < NT; ++nt)
                acc[mt][nt] = __builtin_amdgcn_mfma_f32_16x16x32_bf16(
                    af[mt], bf[nt], acc[mt][nt], 0, 0, 0);
        __syncthreads();
    }
}

// ---------------------------------------------------------------------------
// Prep (one launch): blocks 0..2047 convert x; 2048..3071 transpose W;
// 3072..4095 pack mask (4 rows/uint: byte r = row 4*rr+r).
// ---------------------------------------------------------------------------
__global__ __launch_bounds__(256) void prep_kernel(
    const float* __restrict__ x,
    const float* __restrict__ Wq, const float* __restrict__ Wk,
    const float* __restrict__ Wv, const float* __restrict__ Wo,
    const int* __restrict__ mask,
    bf16_t* __restrict__ xb, bf16_t* __restrict__ wt,
    unsigned int* __restrict__ mp)
{
    __shared__ float tile[32][33];
    const int bid = blockIdx.x, t = threadIdx.x;
    if (bid < 2048) {
        int idx = bid * 256 + t;
        float4 v = ((const float4*)x)[idx];
        bf16x4 o = { (bf16_t)v.x, (bf16_t)v.y, (bf16_t)v.z, (bf16_t)v.w };
        ((bf16x4*)xb)[idx] = o;
    } else if (bid < 3072) {
        int f = bid - 2048;
        int bx = f & 15, by = (f >> 4) & 15, z = f >> 8;
        const float* src = (z == 0) ? Wq : (z == 1) ? Wk : (z == 2) ? Wv : Wo;
        bf16_t* dst = wt + (size_t)z * DIMD * INNER;
        const int tx = t & 31, ty = t >> 5;
        const int rBase = by * 32, cBase = bx * 32;
        #pragma unroll
        for (int i = 0; i < 4; ++i)
            tile[ty + i * 8][tx] = src[(size_t)(rBase + ty + i * 8) * INNER + cBase + tx];
        __syncthreads();
        #pragma unroll
        for (int i = 0; i < 4; ++i)
            dst[(size_t)(cBase + ty + i * 8) * DIMD + rBase + tx] = (bf16_t)tile[tx][ty + i * 8];
    } else {
        int f = bid - 3072;
        int rr = f & 255, b = f >> 8;
        const int* mb = mask + ((size_t)(b * NTOK + rr * 4)) * NTOK;
        #pragma unroll
        for (int u = 0; u < 4; ++u) {
            int col = u * 256 + t;
            unsigned int o = (unsigned)mb[col]
                           | ((unsigned)mb[NTOK + col] << 8)
                           | ((unsigned)mb[2 * NTOK + col] << 16)
                           | ((unsigned)mb[3 * NTOK + col] << 24);
            mp[((size_t)b * 256 + rr) * NTOK + col] = o;
        }
    }
}

// ---------------------------------------------------------------------------
// QKV projection, TM=64 tiles (768 blocks -> 3/CU), fused q/k row-norms.
// Wave wn covers exactly one head (64 cols).
// ---------------------------------------------------------------------------
__global__ __launch_bounds__(256) void qkv_gemm(
    const bf16_t* __restrict__ xb, const bf16_t* __restrict__ wt,
    const float* __restrict__ bq, const float* __restrict__ bk,
    const float* __restrict__ bv,
    bf16_t* __restrict__ qb, bf16_t* __restrict__ kb, bf16_t* __restrict__ vt,
    float* __restrict__ iqn, float* __restrict__ ikn)
{
    __shared__ __align__(16) bf16_t As[2 * 64 * 32];    // 8 KB
    __shared__ __align__(16) bf16_t Bs[2 * 128 * 32];   // 16 KB
    const int z = blockIdx.z;
    const bf16_t* Bp = wt + (size_t)z * DIMD * INNER;
    const float* bias = (z == 0) ? bq : (z == 1) ? bk : bv;
    const int rowBase = blockIdx.y * 64, colBase = blockIdx.x * 128;

    f32x4 acc[2][4] = {};
    gemm_core<64, 128, 2, 4>(xb + (size_t)rowBase * DIMD, DIMD,
                             Bp + (size_t)colBase * DIMD, DIMD, DIMD,
                             As, Bs, acc);

    const int l = threadIdx.x & 63, w = threadIdx.x >> 6;
    const int wm = w >> 1, wn = w & 1;
    float nsum[2][4] = {};
    #pragma unroll
    for (int mt = 0; mt < 2; ++mt)
        #pragma unroll
        for (int nt = 0; nt < 4; ++nt)
            #pragma unroll
            for (int r = 0; r < 4; ++r) {
                int grow = rowBase + wm * 32 + mt * 16 + (l >> 4) * 4 + r;
                int gcol = colBase + wn * 64 + nt * 16 + (l & 15);
                float val = acc[mt][nt][r] + bias[gcol];
                bf16_t vb16 = (bf16_t)val;
                int b = grow >> 10, n = grow & 1023, h = gcol >> 6, d = gcol & 63;
                if (z == 0)
                    qb[(((size_t)b * HH + h) * NTOK + n) * DH + d] = vb16;
                else if (z == 1)
                    kb[(((size_t)b * HH + h) * NTOK + n) * DH + d] = vb16;
                else
                    vt[(((size_t)b * HH + h) * DH + d) * NTOK + n] = vb16;
                if (z < 2) { float vb = (float)vb16; nsum[mt][r] += vb * vb; }
            }
    if (z < 2) {
        float* dst = (z == 0) ? iqn : ikn;
        const int h = (colBase >> 6) + wn;
        #pragma unroll
        for (int mt = 0; mt < 2; ++mt)
            #pragma unroll
            for (int r = 0; r < 4; ++r) {
                float s = nsum[mt][r];
                s += __shfl_xor(s, 8); s += __shfl_xor(s, 4);
                s += __shfl_xor(s, 2); s += __shfl_xor(s, 1);
                if ((l & 15) == 0) {
                    int grow = rowBase + wm * 32 + mt * 16 + (l >> 4) * 4 + r;
                    int b = grow >> 10, n = grow & 1023;
                    dst[((size_t)b * HH + h) * NTOK + n] = 1.0f / sqrtf(s);
                }
            }
    }
}

// ---------------------------------------------------------------------------
// Fused attention, 8-wave column-split (waves 0-3: cols 0-511, waves 4-7:
// cols 512-1023; 64 q-rows/block). Pass A: QK + stats, scores CACHED in
// VGPRs (sacc[8][4] = 128 regs, static indexing only). Pass B: probs from
// cached scores -> fp32 attnf once -> PV. K and V time-share one ping-pong
// LDS region (pass B needs no K). One barrier per tile (stage-ahead).
// ---------------------------------------------------------------------------
__global__ __launch_bounds__(512) void attn_fused(
    const bf16_t* __restrict__ qb, const bf16_t* __restrict__ kb,
    const bf16_t* __restrict__ vt, const unsigned int* __restrict__ mp,
    const float* __restrict__ iqn, const float* __restrict__ ikn,
    float* __restrict__ attnf, bf16_t* __restrict__ ctxb,
    float* __restrict__ cl, float* __restrict__ rg)
{
    __shared__ __align__(16) bf16_t KV[2][2][64 * 64]; // 32 KB ping-pong, K then V
    __shared__ __align__(16) bf16_t Ps[8][16 * 64];    // 16 KB, per-wave
    __shared__ float4 sred[8][16];                     // 2 KB stats exchange
    const int bh = blockIdx.y;
    const int b = bh >> 3, h = bh & 7;
    const int rowBase = blockIdx.x * 64;
    const bf16_t* Q = qb + (size_t)bh * NTOK * DH;
    const bf16_t* K = kb + (size_t)bh * NTOK * DH;
    const bf16_t* V = vt + (size_t)bh * DH * NTOK;
    const float* iknr = ikn + (size_t)bh * NTOK;
    const int t = threadIdx.x, w = t >> 6, l = t & 63;
    const int half = w >> 2, rw = w & 3;
    const int l15 = l & 15, q = l >> 4;
    bf16_t* Pw = Ps[w];

    auto stageK = [&](int tt, int buf) {
        #pragma unroll
        for (int u = 0; u < 2; ++u) {
            int g = (u * 8 + w) * 64 + l;
            int hh = g >> 9, kr = (g >> 3) & 63, ci = g & 7;
            gload_lds16(K + (size_t)(hh * 512 + tt * 64 + kr) * DH + ((ci * 8) ^ ((kr & 7) << 3)),
                        &KV[buf][0][0] + (size_t)(u * 8 + w) * 512);
        }
    };
    auto stageV = [&](int tt, int buf) {
        #pragma unroll
        for (int u = 0; u < 2; ++u) {
            int g = (u * 8 + w) * 64 + l;
            int hh = g >> 9, d = (g >> 3) & 63, ci = g & 7;
            gload_lds16(V + (size_t)d * NTOK + hh * 512 + tt * 64 + ((ci * 8) ^ ((d & 7) << 3)),
                        &KV[buf][0][0] + (size_t)(u * 8 + w) * 512);
        }
    };

    bf16x8 af[2];
    {
        const bf16_t* qrow = Q + (size_t)(rowBase + rw * 16 + l15) * DH + q * 8;
        af[0] = *(const bf16x8*)(qrow);
        af[1] = *(const bf16x8*)(qrow + 32);
    }
    const int tok = rowBase + rw * 16 + q * 4;     // first of this thread's 4 rows
    float iqn4[4];
    #pragma unroll
    for (int r = 0; r < 4; ++r)
        iqn4[r] = iqn[(size_t)bh * NTOK + tok + r];
    const unsigned int* mrow = mp + ((size_t)b * 256 + (tok >> 2)) * NTOK;

    f32x4 sacc[8][4] = {};          // cached scores: 128 VGPR, static idx only
    unsigned int mmc[8][4];         // cached packed mask: 32 VGPR
    float alls[4] = {}, pos[4] = {}, esum[4] = {}, regf[4] = {};

    // ---- pass A: QK + stats (K ping-pong, 1 barrier/tile) ----
    stageK(0, 0);
    __syncthreads();
    #pragma unroll
    for (int tt = 0; tt < 8; ++tt) {
        const int col0 = half * 512 + tt * 64;
        if (tt < 7) stageK(tt + 1, (tt + 1) & 1);
        float ik4[4];
        #pragma unroll
        for (int nt = 0; nt < 4; ++nt) {
            int c = col0 + nt * 16 + l15;
            mmc[tt][nt] = mrow[c];
            ik4[nt] = iknr[c];
        }
        const bf16_t* Kh = &KV[tt & 1][half][0];
        #pragma unroll
        for (int ks = 0; ks < 2; ++ks) {
            int koff = ks * 32 + q * 8;
            #pragma unroll
            for (int nt = 0; nt < 4; ++nt) {
                int kr = nt * 16 + l15;
                bf16x8 bfk = *(const bf16x8*)&Kh[kr * 64 + swz(kr, koff)];
                sacc[tt][nt] = __builtin_amdgcn_mfma_f32_16x16x32_bf16(af[ks], bfk, sacc[tt][nt], 0, 0, 0);
            }
        }
        #pragma unroll
        for (int nt = 0; nt < 4; ++nt) {
            float ik = ik4[nt];
            unsigned int mm = mmc[tt][nt];
            #pragma unroll
            for (int r = 0; r < 4; ++r) {
                float s = sacc[tt][nt][r];
                float mbit = (float)((mm >> (8 * r)) & 1u);
                float e1 = __expf(s * iqn4[r] * ik * INV_TEMP);
                float e2 = __expf(s * SCALE);
                alls[r] += e1;
                pos[r]  += e1 * mbit;
                esum[r] += e2 * mbit;   // masked entries contribute exactly 0
                regf[r] += mbit;
            }
        }
        __syncthreads();
    }
    // wave-local butterfly over the 16 lanes sharing each row
    #pragma unroll
    for (int r = 0; r < 4; ++r) {
        #pragma unroll
        for (int off = 8; off; off >>= 1) {
            alls[r] += __shfl_xor(alls[r], off);
            pos[r]  += __shfl_xor(pos[r], off);
            esum[r] += __shfl_xor(esum[r], off);
            regf[r] += __shfl_xor(regf[r], off);
        }
    }
    // cross-half combine
    if (l15 == 0) {
        #pragma unroll
        for (int r = 0; r < 4; ++r)
            sred[w][q * 4 + r] = make_float4(alls[r], pos[r], esum[r], regf[r]);
    }
    __syncthreads();
    float inv4[4];
    #pragma unroll
    for (int r = 0; r < 4; ++r) {
        float4 o = sred[w ^ 4][q * 4 + r];
        float allsT = alls[r] + o.x;
        float posT  = pos[r]  + o.y;
        float esumT = esum[r] + o.z;
        float regT  = regf[r] + o.w;
        inv4[r] = 1.0f / esumT;
        if (half == 0 && l15 == 0) {
            int rowG = bh * NTOK + tok + r;
            cl[rowG] = logf(allsT) - logf(posT);
            if (h == 0) rg[b * NTOK + tok + r] = regT - 1.0f;
        }
    }

    // ---- pass B: probs + PV from cached scores (V ping-pong in KV region) ----
    float* prow = attnf + ((size_t)bh * NTOK + tok) * NTOK;
    f32x4 cacc[4] = {};
    stageV(0, 0);
    __syncthreads();
    #pragma unroll
    for (int tt = 0; tt < 8; ++tt) {
        const int col0 = half * 512 + tt * 64;
        if (tt < 7) stageV(tt + 1, (tt + 1) & 1);
        #pragma unroll
        for (int nt = 0; nt < 4; ++nt) {
            int c = nt * 16 + l15;
            unsigned int mm = mmc[tt][nt];
            #pragma unroll
            for (int r = 0; r < 4; ++r) {
                float p = ((mm >> (8 * r)) & 1u)
                        ? __expf(sacc[tt][nt][r] * SCALE) * inv4[r] : 0.0f;
                prow[(size_t)r * NTOK + col0 + c] = p;
                int pr = q * 4 + r;
                Pw[pr * 64 + swz(pr, c)] = (bf16_t)p;
            }
        }
        const bf16_t* Vh = &KV[tt & 1][half][0];
        #pragma unroll
        for (int ks = 0; ks < 2; ++ks) {
            int koff = ks * 32 + q * 8;
            bf16x8 afp = *(const bf16x8*)&Pw[l15 * 64 + swz(l15, koff)];
            #pragma unroll
            for (int nt = 0; nt < 4; ++nt) {
                int d = nt * 16 + l15;
                bf16x8 bfv = *(const bf16x8*)&Vh[d * 64 + swz(d, koff)];
                cacc[nt] = __builtin_amdgcn_mfma_f32_16x16x32_bf16(afp, bfv, cacc[nt], 0, 0, 0);
            }
        }
        __syncthreads();
    }
    // cross-half PV combine through retired Ps region (exactly 16 KB)
    float* cred = (float*)&Ps[0][0];
    if (half == 1) {
        #pragma unroll
        for (int nt = 0; nt < 4; ++nt)
            #pragma unroll
            for (int r = 0; r < 4; ++r)
                cred[(size_t)rw * 1024 + (q * 4 + r) * 64 + nt * 16 + l15] = cacc[nt][r];
    }
    __syncthreads();
    if (half == 0) {
        #pragma unroll
        for (int nt = 0; nt < 4; ++nt)
            #pragma unroll
            for (int r = 0; r < 4; ++r) {
                float v = cacc[nt][r] + cred[(size_t)rw * 1024 + (q * 4 + r) * 64 + nt * 16 + l15];
                int n = tok + r;
                int d = nt * 16 + l15;
                ctxb[((size_t)b * NTOK + n) * INNER + h * DH + d] = (bf16_t)v;
            }
    }
}

// ---------------------------------------------------------------------------
// Block reduction helper (256 threads)
// ---------------------------------------------------------------------------
__device__ __forceinline__ float block_sum(float v, float* sh)
{
    #pragma unroll
    for (int off = 32; off; off >>= 1) v += __shfl_down(v, off);
    __syncthreads();
    if ((threadIdx.x & 63) == 0) sh[threadIdx.x >> 6] = v;
    __syncthreads();
    return sh[0] + sh[1] + sh[2] + sh[3];
}

// ---------------------------------------------------------------------------
// Out projection, TM=64 tiles (256 blocks -> all CUs), + DCL finalize in (0,0)
// ---------------------------------------------------------------------------
__global__ __launch_bounds__(256) void out_gemm(
    const bf16_t* __restrict__ ctxb, const bf16_t* __restrict__ wt,
    const float* __restrict__ bo, float* __restrict__ outp,
    const float* __restrict__ cl, const float* __restrict__ rg,
    float* __restrict__ dcl)
{
    __shared__ __align__(16) bf16_t As[2 * 64 * 32];    // 8 KB
    __shared__ __align__(16) bf16_t Bs[2 * 128 * 32];   // 16 KB
    __shared__ float sh4[4];
    const int rowBase = blockIdx.y * 64, colBase = blockIdx.x * 128;
    const bf16_t* Wot = wt + (size_t)3 * DIMD * INNER;

    f32x4 acc[2][4] = {};
    gemm_core<64, 128, 2, 4>(ctxb + (size_t)rowBase * INNER, INNER,
                             Wot + (size_t)colBase * INNER, INNER, INNER,
                             As, Bs, acc);

    const int l = threadIdx.x & 63, w = threadIdx.x >> 6;
    const int wm = w >> 1, wn = w & 1;
    #pragma unroll
    for (int mt = 0; mt < 2; ++mt)
        #pragma unroll
        for (int nt = 0; nt < 4; ++nt)
            #pragma unroll
            for (int r = 0; r < 4; ++r) {
                int grow = rowBase + wm * 32 + mt * 16 + (l >> 4) * 4 + r;
                int gcol = colBase + wn * 64 + nt * 16 + (l & 15);
                outp[(size_t)grow * DIMD + gcol] = acc[mt][nt][r] + bo[gcol];
            }

    if (blockIdx.x == 0 && blockIdx.y == 0) {
        float s1 = 0.f, s2 = 0.f;
        for (int idx = threadIdx.x; idx < BH * NTOK; idx += 256) s1 += cl[idx];
        for (int idx = threadIdx.x; idx < BB * NTOK; idx += 256) s2 += rg[idx];
        __syncthreads();
        s1 = block_sum(s1, sh4);
        s2 = block_sum(s2, sh4);
        if (threadIdx.x == 0) {
            dcl[0] = s1 * (1.0f / (float)(BB * HH * NTOK))
                   + 0.3f * s2 * (1.0f / ((float)NTOK * (float)(NTOK - 1) * (float)BB));
        }
    }
}

// ---------------------------------------------------------------------------
extern "C" void kernel_launch(void* const* d_in, const int* in_sizes, int n_in,
                              void* d_out, int out_size, void* d_ws, size_t ws_size,
                              hipStream_t stream)
{
    const float* x  = (const float*)d_in[0];
    const int* mask = (const int*)d_in[1];
    const float* Wq = (const float*)d_in[2];
    const float* bq = (const float*)d_in[3];
    const float* Wk = (const float*)d_in[4];
    const float* bk = (const float*)d_in[5];
    const float* Wv = (const float*)d_in[6];
    const float* bv = (const float*)d_in[7];
    const float* Wo = (const float*)d_in[8];
    const float* bo = (const float*)d_in[9];

    float* out   = (float*)d_out;                        // [4096, 512]
    float* attnf = out + (size_t)ROWS * DIMD;            // [32,1024,1024] fp32 probs
    float* dcl   = attnf + (size_t)BH * NTOK * NTOK;     // scalar

    // ws layout (bf16 regions first, all 16B-aligned); ~27 MB total
    char* wsb = (char*)d_ws;
    bf16_t* xb    = (bf16_t*)wsb;                              // 4 MB
    bf16_t* wt    = xb + (size_t)ROWS * DIMD;                  // 2 MB (4x 512x512)
    bf16_t* qb    = wt + (size_t)4 * DIMD * INNER;             // 4 MB
    bf16_t* kb    = qb + (size_t)BH * NTOK * DH;               // 4 MB
    bf16_t* vt    = kb + (size_t)BH * NTOK * DH;               // 4 MB
    bf16_t* ctxb  = vt + (size_t)BH * NTOK * DH;               // 4 MB
    float*  iqn   = (float*)(ctxb + (size_t)ROWS * INNER);     // 128 KB
    float*  ikn   = iqn + BH * NTOK;                           // 128 KB
    float*  cl    = ikn + BH * NTOK;                           // 128 KB
    float*  rg    = cl + BH * NTOK;                            // 16 KB
    unsigned int* mpk = (unsigned int*)(rg + BB * NTOK);       // 4 MB packed mask

    dim3 blk(256);
    prep_kernel<<<dim3(4096), blk, 0, stream>>>(x, Wq, Wk, Wv, Wo, mask, xb, wt, mpk);
    qkv_gemm<<<dim3(4, 64, 3), blk, 0, stream>>>(xb, wt, bq, bk, bv, qb, kb, vt, iqn, ikn);
    attn_fused<<<dim3(16, 32), dim3(512), 0, stream>>>(qb, kb, vt, mpk, iqn, ikn, attnf, ctxb, cl, rg);
    out_gemm<<<dim3(4, 64), blk, 0, stream>>>(ctxb, wt, bo, out, cl, rg, dcl);
}

// Round 5
// 271.060 us; speedup vs baseline: 1.0431x; 1.0431x over previous
//
#include <hip/hip_runtime.h>
#include <hip/hip_bf16.h>
#include <math.h>

#define BB 4
#define NTOK 1024
#define DIMD 512
#define HH 8
#define DH 64
#define INNER 512
#define BH (BB*HH)          // 32
#define ROWS (BB*NTOK)      // 4096
#define SCALE 0.125f
#define INV_TEMP 10.0f

typedef __bf16 bf16_t;
using bf16x4 = __attribute__((ext_vector_type(4))) __bf16;
using bf16x8 = __attribute__((ext_vector_type(8))) __bf16;
using f32x4  = __attribute__((ext_vector_type(4))) float;

// XOR swizzle (element units, bf16): flips elem bits 3-5 by row -> spreads a
// b128 read across banks for 128B-row tiles; bijective within 64-el rows. [G4]
__device__ __forceinline__ int swz(int row, int e) { return e ^ ((row & 7) << 3); }

// Async global->LDS 16B: LDS dest is wave-uniform base + lane*16 (linear).
// Swizzled layouts are achieved by pre-swizzling the SOURCE address (m173).
__device__ __forceinline__ void gload_lds16(const bf16_t* g, bf16_t* l)
{
    __builtin_amdgcn_global_load_lds(
        (const __attribute__((address_space(1))) void*)g,
        (__attribute__((address_space(3))) void*)l, 16, 0, 0);
}

// ---------------------------------------------------------------------------
// Shared MFMA GEMM core (qkv_gemm / out_gemm): C[TM,TN] += A[TM,K]*B[TN,K]^T
// Ping-pong double-buffer, ONE barrier per K-step: stage(k+1) issues before
// compute(k); the compiler's vmcnt/lgkm drain at __syncthreads gives safety.
//   A frag (lane l): A[m = l&15][k = (l>>4)*8 + j]
//   C/D (lane l, reg r): row = (l>>4)*4 + r, col = l&15   [m89/m91 verified]
// As sized 2*TM*32, Bs sized 2*TN*32.
// ---------------------------------------------------------------------------
template<int TM, int TN, int MT, int NT>
__device__ __forceinline__ void gemm_core(
    const bf16_t* __restrict__ A, int ldA,
    const bf16_t* __restrict__ B, int ldB, int K,
    bf16_t* As, bf16_t* Bs, f32x4 (&acc)[MT][NT])
{
    const int t = threadIdx.x;
    const int w = t >> 6, l = t & 63;
    constexpr int WGN = TN / (NT * 16);
    const int wm = w / WGN, wn = w % WGN;
    const int lrow = l & 15, lk = (l >> 4) * 8;
    constexpr int ASZ = TM * 32, BSZ = TN * 32;

    auto stage = [&](int k0, int buf) {
        #pragma unroll
        for (int it = 0; it < TM / 64; ++it)
            gload_lds16(&A[(size_t)((t >> 2) + it * 64) * ldA + k0 + (t & 3) * 8],
                        As + buf * ASZ + ((size_t)it * 256 + w * 64) * 8);
        #pragma unroll
        for (int it = 0; it < TN / 64; ++it)
            gload_lds16(&B[(size_t)((t >> 2) + it * 64) * ldB + k0 + (t & 3) * 8],
                        Bs + buf * BSZ + ((size_t)it * 256 + w * 64) * 8);
    };

    stage(0, 0);
    __syncthreads();
    for (int k0 = 0; k0 < K; k0 += 32) {
        const int cur = (k0 >> 5) & 1;
        if (k0 + 32 < K) stage(k0 + 32, cur ^ 1);
        const bf16_t* Ac = As + cur * ASZ;
        const bf16_t* Bc = Bs + cur * BSZ;
        bf16x8 af[MT], bf[NT];
        #pragma unroll
        for (int mt = 0; mt < MT; ++mt)
            af[mt] = *(const bf16x8*)&Ac[(wm * MT * 16 + mt * 16 + lrow) * 32 + lk];
        #pragma unroll
        for (int nt = 0; nt < NT; ++nt)
            bf[nt] = *(const bf16x8*)&Bc[(wn * NT * 16 + nt * 16 + lrow) * 32 + lk];
        #pragma unroll
        for (int mt = 0; mt < MT; ++mt)
            #pragma unroll
            for (int nt = 0; nt < NT; ++nt)
                acc[mt][nt] = __builtin_amdgcn_mfma_f32_16x16x32_bf16(
                    af[mt], bf[nt], acc[mt][nt], 0, 0, 0);
        __syncthreads();
    }
}

// ---------------------------------------------------------------------------
// Prep (one launch): blocks 0..2047 convert x; 2048..3071 transpose W;
// 3072..4095 pack mask (4 rows/uint: byte r = row 4*rr+r).
// ---------------------------------------------------------------------------
__global__ __launch_bounds__(256) void prep_kernel(
    const float* __restrict__ x,
    const float* __restrict__ Wq, const float* __restrict__ Wk,
    const float* __restrict__ Wv, const float* __restrict__ Wo,
    const int* __restrict__ mask,
    bf16_t* __restrict__ xb, bf16_t* __restrict__ wt,
    unsigned int* __restrict__ mp)
{
    __shared__ float tile[32][33];
    const int bid = blockIdx.x, t = threadIdx.x;
    if (bid < 2048) {
        int idx = bid * 256 + t;
        float4 v = ((const float4*)x)[idx];
        bf16x4 o = { (bf16_t)v.x, (bf16_t)v.y, (bf16_t)v.z, (bf16_t)v.w };
        ((bf16x4*)xb)[idx] = o;
    } else if (bid < 3072) {
        int f = bid - 2048;
        int bx = f & 15, by = (f >> 4) & 15, z = f >> 8;
        const float* src = (z == 0) ? Wq : (z == 1) ? Wk : (z == 2) ? Wv : Wo;
        bf16_t* dst = wt + (size_t)z * DIMD * INNER;
        const int tx = t & 31, ty = t >> 5;
        const int rBase = by * 32, cBase = bx * 32;
        #pragma unroll
        for (int i = 0; i < 4; ++i)
            tile[ty + i * 8][tx] = src[(size_t)(rBase + ty + i * 8) * INNER + cBase + tx];
        __syncthreads();
        #pragma unroll
        for (int i = 0; i < 4; ++i)
            dst[(size_t)(cBase + ty + i * 8) * DIMD + rBase + tx] = (bf16_t)tile[tx][ty + i * 8];
    } else {
        int f = bid - 3072;
        int rr = f & 255, b = f >> 8;
        const int* mb = mask + ((size_t)(b * NTOK + rr * 4)) * NTOK;
        #pragma unroll
        for (int u = 0; u < 4; ++u) {
            int col = u * 256 + t;
            unsigned int o = (unsigned)mb[col]
                           | ((unsigned)mb[NTOK + col] << 8)
                           | ((unsigned)mb[2 * NTOK + col] << 16)
                           | ((unsigned)mb[3 * NTOK + col] << 24);
            mp[((size_t)b * 256 + rr) * NTOK + col] = o;
        }
    }
}

// ---------------------------------------------------------------------------
// QKV projection, TM=64 tiles (768 blocks -> 3/CU), fused q/k row-norms.
// Wave wn covers exactly one head (64 cols).
// ---------------------------------------------------------------------------
__global__ __launch_bounds__(256) void qkv_gemm(
    const bf16_t* __restrict__ xb, const bf16_t* __restrict__ wt,
    const float* __restrict__ bq, const float* __restrict__ bk,
    const float* __restrict__ bv,
    bf16_t* __restrict__ qb, bf16_t* __restrict__ kb, bf16_t* __restrict__ vt,
    float* __restrict__ iqn, float* __restrict__ ikn)
{
    __shared__ __align__(16) bf16_t As[2 * 64 * 32];    // 8 KB
    __shared__ __align__(16) bf16_t Bs[2 * 128 * 32];   // 16 KB
    const int z = blockIdx.z;
    const bf16_t* Bp = wt + (size_t)z * DIMD * INNER;
    const float* bias = (z == 0) ? bq : (z == 1) ? bk : bv;
    const int rowBase = blockIdx.y * 64, colBase = blockIdx.x * 128;

    f32x4 acc[2][4] = {};
    gemm_core<64, 128, 2, 4>(xb + (size_t)rowBase * DIMD, DIMD,
                             Bp + (size_t)colBase * DIMD, DIMD, DIMD,
                             As, Bs, acc);

    const int l = threadIdx.x & 63, w = threadIdx.x >> 6;
    const int wm = w >> 1, wn = w & 1;
    float nsum[2][4] = {};
    #pragma unroll
    for (int mt = 0; mt < 2; ++mt)
        #pragma unroll
        for (int nt = 0; nt < 4; ++nt)
            #pragma unroll
            for (int r = 0; r < 4; ++r) {
                int grow = rowBase + wm * 32 + mt * 16 + (l >> 4) * 4 + r;
                int gcol = colBase + wn * 64 + nt * 16 + (l & 15);
                float val = acc[mt][nt][r] + bias[gcol];
                bf16_t vb16 = (bf16_t)val;
                int b = grow >> 10, n = grow & 1023, h = gcol >> 6, d = gcol & 63;
                if (z == 0)
                    qb[(((size_t)b * HH + h) * NTOK + n) * DH + d] = vb16;
                else if (z == 1)
                    kb[(((size_t)b * HH + h) * NTOK + n) * DH + d] = vb16;
                else
                    vt[(((size_t)b * HH + h) * DH + d) * NTOK + n] = vb16;
                if (z < 2) { float vb = (float)vb16; nsum[mt][r] += vb * vb; }
            }
    if (z < 2) {
        float* dst = (z == 0) ? iqn : ikn;
        const int h = (colBase >> 6) + wn;
        #pragma unroll
        for (int mt = 0; mt < 2; ++mt)
            #pragma unroll
            for (int r = 0; r < 4; ++r) {
                float s = nsum[mt][r];
                s += __shfl_xor(s, 8); s += __shfl_xor(s, 4);
                s += __shfl_xor(s, 2); s += __shfl_xor(s, 1);
                if ((l & 15) == 0) {
                    int grow = rowBase + wm * 32 + mt * 16 + (l >> 4) * 4 + r;
                    int b = grow >> 10, n = grow & 1023;
                    dst[((size_t)b * HH + h) * NTOK + n] = 1.0f / sqrtf(s);
                }
            }
    }
}

// ---------------------------------------------------------------------------
// Fused attention (R3 structure: no VGPR score cache -> stays under the
// 128-VGPR occupancy cliff, 16 waves/CU). 8-wave column-split: waves 0-3 =
// rows (4x16) over cols 0-511, waves 4-7 same rows over cols 512-1023.
// KVBLK=64, LDS 50 KB. Pass A: QK + DCL/softmax stats (cross-half LDS
// combine). Pass B: QK recompute -> fp32 probs once -> PV (partials combined
// through the retired Ps region).
// ---------------------------------------------------------------------------
__global__ __launch_bounds__(512) void attn_fused(
    const bf16_t* __restrict__ qb, const bf16_t* __restrict__ kb,
    const bf16_t* __restrict__ vt, const unsigned int* __restrict__ mp,
    const float* __restrict__ iqn, const float* __restrict__ ikn,
    float* __restrict__ attnf, bf16_t* __restrict__ ctxb,
    float* __restrict__ cl, float* __restrict__ rg)
{
    __shared__ __align__(16) bf16_t Ks[2][64 * 64];   // 16 KB (both col-halves)
    __shared__ __align__(16) bf16_t Vs[2][64 * 64];   // 16 KB
    __shared__ __align__(16) bf16_t Ps[8][16 * 64];   // 16 KB, per-wave
    __shared__ float4 sred[8][16];                    // 2 KB stats exchange
    const int bh = blockIdx.y;
    const int b = bh >> 3, h = bh & 7;
    const int rowBase = blockIdx.x * 64;
    const bf16_t* Q = qb + (size_t)bh * NTOK * DH;
    const bf16_t* K = kb + (size_t)bh * NTOK * DH;
    const bf16_t* V = vt + (size_t)bh * DH * NTOK;
    const float* iknr = ikn + (size_t)bh * NTOK;
    const int t = threadIdx.x, w = t >> 6, l = t & 63;
    const int half = w >> 2, rw = w & 3;
    const int l15 = l & 15, q = l >> 4;
    bf16_t* Pw = Ps[w];

    bf16x8 af[2];
    {
        const bf16_t* qrow = Q + (size_t)(rowBase + rw * 16 + l15) * DH + q * 8;
        af[0] = *(const bf16x8*)(qrow);
        af[1] = *(const bf16x8*)(qrow + 32);
    }
    const int tok = rowBase + rw * 16 + q * 4;     // first of this thread's 4 rows
    float iqn4[4];
    #pragma unroll
    for (int r = 0; r < 4; ++r)
        iqn4[r] = iqn[(size_t)bh * NTOK + tok + r];
    const unsigned int* mrow = mp + ((size_t)b * 256 + (tok >> 2)) * NTOK;

    float alls[4] = {}, pos[4] = {}, esum[4] = {}, regf[4] = {};

    // ---- pass A: stats ----
    for (int tt = 0; tt < 8; ++tt) {
        const int col0 = half * 512 + tt * 64;
        #pragma unroll
        for (int u = 0; u < 2; ++u) {               // stage K, both halves
            int g = (u * 8 + w) * 64 + l;
            int hh = g >> 9, kr = (g >> 3) & 63, ci = g & 7;
            gload_lds16(K + (size_t)(hh * 512 + tt * 64 + kr) * DH + ((ci * 8) ^ ((kr & 7) << 3)),
                        &Ks[0][0] + (size_t)(u * 8 + w) * 512);
        }
        unsigned int mm4[4]; float ik4[4];
        #pragma unroll
        for (int nt = 0; nt < 4; ++nt) {
            int c = col0 + nt * 16 + l15;
            mm4[nt] = mrow[c];
            ik4[nt] = iknr[c];
        }
        __syncthreads();
        f32x4 sacc[4] = {};
        #pragma unroll
        for (int ks = 0; ks < 2; ++ks) {
            int koff = ks * 32 + q * 8;
            #pragma unroll
            for (int nt = 0; nt < 4; ++nt) {
                int kr = nt * 16 + l15;
                bf16x8 bfk = *(const bf16x8*)&Ks[half][kr * 64 + swz(kr, koff)];
                sacc[nt] = __builtin_amdgcn_mfma_f32_16x16x32_bf16(af[ks], bfk, sacc[nt], 0, 0, 0);
            }
        }
        #pragma unroll
        for (int nt = 0; nt < 4; ++nt) {
            float ik = ik4[nt];
            unsigned int mm = mm4[nt];
            #pragma unroll
            for (int r = 0; r < 4; ++r) {
                float s = sacc[nt][r];
                float mbit = (float)((mm >> (8 * r)) & 1u);
                float e1 = __expf(s * iqn4[r] * ik * INV_TEMP);
                float e2 = __expf(s * SCALE);
                alls[r] += e1;
                pos[r]  += e1 * mbit;
                esum[r] += e2 * mbit;   // masked entries contribute exactly 0
                regf[r] += mbit;
            }
        }
        __syncthreads();
    }
    // wave-local butterfly over the 16 lanes sharing each row
    #pragma unroll
    for (int r = 0; r < 4; ++r) {
        #pragma unroll
        for (int off = 8; off; off >>= 1) {
            alls[r] += __shfl_xor(alls[r], off);
            pos[r]  += __shfl_xor(pos[r], off);
            esum[r] += __shfl_xor(esum[r], off);
            regf[r] += __shfl_xor(regf[r], off);
        }
    }
    // cross-half combine
    if (l15 == 0) {
        #pragma unroll
        for (int r = 0; r < 4; ++r)
            sred[w][q * 4 + r] = make_float4(alls[r], pos[r], esum[r], regf[r]);
    }
    __syncthreads();
    float inv4[4];
    #pragma unroll
    for (int r = 0; r < 4; ++r) {
        float4 o = sred[w ^ 4][q * 4 + r];
        float allsT = alls[r] + o.x;
        float posT  = pos[r]  + o.y;
        float esumT = esum[r] + o.z;
        float regT  = regf[r] + o.w;
        inv4[r] = 1.0f / esumT;
        if (half == 0 && l15 == 0) {
            int rowG = bh * NTOK + tok + r;
            cl[rowG] = logf(allsT) - logf(posT);
            if (h == 0) rg[b * NTOK + tok + r] = regT - 1.0f;
        }
    }

    // ---- pass B: probs + PV ----
    float* prow = attnf + ((size_t)bh * NTOK + tok) * NTOK;
    f32x4 cacc[4] = {};
    for (int tt = 0; tt < 8; ++tt) {
        const int col0 = half * 512 + tt * 64;
        #pragma unroll
        for (int u = 0; u < 2; ++u) {               // stage K
            int g = (u * 8 + w) * 64 + l;
            int hh = g >> 9, kr = (g >> 3) & 63, ci = g & 7;
            gload_lds16(K + (size_t)(hh * 512 + tt * 64 + kr) * DH + ((ci * 8) ^ ((kr & 7) << 3)),
                        &Ks[0][0] + (size_t)(u * 8 + w) * 512);
        }
        #pragma unroll
        for (int u = 0; u < 2; ++u) {               // stage V
            int g = (u * 8 + w) * 64 + l;
            int hh = g >> 9, d = (g >> 3) & 63, ci = g & 7;
            gload_lds16(V + (size_t)d * NTOK + hh * 512 + tt * 64 + ((ci * 8) ^ ((d & 7) << 3)),
                        &Vs[0][0] + (size_t)(u * 8 + w) * 512);
        }
        unsigned int mm4[4];
        #pragma unroll
        for (int nt = 0; nt < 4; ++nt)
            mm4[nt] = mrow[col0 + nt * 16 + l15];
        __syncthreads();
        f32x4 sacc[4] = {};
        #pragma unroll
        for (int ks = 0; ks < 2; ++ks) {
            int koff = ks * 32 + q * 8;
            #pragma unroll
            for (int nt = 0; nt < 4; ++nt) {
                int kr = nt * 16 + l15;
                bf16x8 bfk = *(const bf16x8*)&Ks[half][kr * 64 + swz(kr, koff)];
                sacc[nt] = __builtin_amdgcn_mfma_f32_16x16x32_bf16(af[ks], bfk, sacc[nt], 0, 0, 0);
            }
        }
        // probs: required fp32 output + bf16 into per-wave P tile
        #pragma unroll
        for (int nt = 0; nt < 4; ++nt) {
            int c = nt * 16 + l15;
            unsigned int mm = mm4[nt];
            #pragma unroll
            for (int r = 0; r < 4; ++r) {
                float p = ((mm >> (8 * r)) & 1u)
                        ? __expf(sacc[nt][r] * SCALE) * inv4[r] : 0.0f;
                prow[(size_t)r * NTOK + col0 + c] = p;
                int pr = q * 4 + r;
                Pw[pr * 64 + swz(pr, c)] = (bf16_t)p;
            }
        }
        // PV: ctx(16x64) += P(16x64) @ V^T(64x64), this col-half's partial
        #pragma unroll
        for (int ks = 0; ks < 2; ++ks) {
            int koff = ks * 32 + q * 8;
            bf16x8 afp = *(const bf16x8*)&Pw[l15 * 64 + swz(l15, koff)];
            #pragma unroll
            for (int nt = 0; nt < 4; ++nt) {
                int d = nt * 16 + l15;
                bf16x8 bfv = *(const bf16x8*)&Vs[half][d * 64 + swz(d, koff)];
                cacc[nt] = __builtin_amdgcn_mfma_f32_16x16x32_bf16(afp, bfv, cacc[nt], 0, 0, 0);
            }
        }
        __syncthreads();
    }
    // cross-half PV combine through retired Ps region (exactly 16 KB)
    float* cred = (float*)&Ps[0][0];
    if (half == 1) {
        #pragma unroll
        for (int nt = 0; nt < 4; ++nt)
            #pragma unroll
            for (int r = 0; r < 4; ++r)
                cred[(size_t)rw * 1024 + (q * 4 + r) * 64 + nt * 16 + l15] = cacc[nt][r];
    }
    __syncthreads();
    if (half == 0) {
        #pragma unroll
        for (int nt = 0; nt < 4; ++nt)
            #pragma unroll
            for (int r = 0; r < 4; ++r) {
                float v = cacc[nt][r] + cred[(size_t)rw * 1024 + (q * 4 + r) * 64 + nt * 16 + l15];
                int n = tok + r;
                int d = nt * 16 + l15;
                ctxb[((size_t)b * NTOK + n) * INNER + h * DH + d] = (bf16_t)v;
            }
    }
}

// ---------------------------------------------------------------------------
// Block reduction helper (256 threads)
// ---------------------------------------------------------------------------
__device__ __forceinline__ float block_sum(float v, float* sh)
{
    #pragma unroll
    for (int off = 32; off; off >>= 1) v += __shfl_down(v, off);
    __syncthreads();
    if ((threadIdx.x & 63) == 0) sh[threadIdx.x >> 6] = v;
    __syncthreads();
    return sh[0] + sh[1] + sh[2] + sh[3];
}

// ---------------------------------------------------------------------------
// Out projection, TM=64 tiles (256 blocks -> all CUs), + DCL finalize in (0,0)
// ---------------------------------------------------------------------------
__global__ __launch_bounds__(256) void out_gemm(
    const bf16_t* __restrict__ ctxb, const bf16_t* __restrict__ wt,
    const float* __restrict__ bo, float* __restrict__ outp,
    const float* __restrict__ cl, const float* __restrict__ rg,
    float* __restrict__ dcl)
{
    __shared__ __align__(16) bf16_t As[2 * 64 * 32];    // 8 KB
    __shared__ __align__(16) bf16_t Bs[2 * 128 * 32];   // 16 KB
    __shared__ float sh4[4];
    const int rowBase = blockIdx.y * 64, colBase = blockIdx.x * 128;
    const bf16_t* Wot = wt + (size_t)3 * DIMD * INNER;

    f32x4 acc[2][4] = {};
    gemm_core<64, 128, 2, 4>(ctxb + (size_t)rowBase * INNER, INNER,
                             Wot + (size_t)colBase * INNER, INNER, INNER,
                             As, Bs, acc);

    const int l = threadIdx.x & 63, w = threadIdx.x >> 6;
    const int wm = w >> 1, wn = w & 1;
    #pragma unroll
    for (int mt = 0; mt < 2; ++mt)
        #pragma unroll
        for (int nt = 0; nt < 4; ++nt)
            #pragma unroll
            for (int r = 0; r < 4; ++r) {
                int grow = rowBase + wm * 32 + mt * 16 + (l >> 4) * 4 + r;
                int gcol = colBase + wn * 64 + nt * 16 + (l & 15);
                outp[(size_t)grow * DIMD + gcol] = acc[mt][nt][r] + bo[gcol];
            }

    if (blockIdx.x == 0 && blockIdx.y == 0) {
        float s1 = 0.f, s2 = 0.f;
        for (int idx = threadIdx.x; idx < BH * NTOK; idx += 256) s1 += cl[idx];
        for (int idx = threadIdx.x; idx < BB * NTOK; idx += 256) s2 += rg[idx];
        __syncthreads();
        s1 = block_sum(s1, sh4);
        s2 = block_sum(s2, sh4);
        if (threadIdx.x == 0) {
            dcl[0] = s1 * (1.0f / (float)(BB * HH * NTOK))
                   + 0.3f * s2 * (1.0f / ((float)NTOK * (float)(NTOK - 1) * (float)BB));
        }
    }
}

// ---------------------------------------------------------------------------
extern "C" void kernel_launch(void* const* d_in, const int* in_sizes, int n_in,
                              void* d_out, int out_size, void* d_ws, size_t ws_size,
                              hipStream_t stream)
{
    const float* x  = (const float*)d_in[0];
    const int* mask = (const int*)d_in[1];
    const float* Wq = (const float*)d_in[2];
    const float* bq = (const float*)d_in[3];
    const float* Wk = (const float*)d_in[4];
    const float* bk = (const float*)d_in[5];
    const float* Wv = (const float*)d_in[6];
    const float* bv = (const float*)d_in[7];
    const float* Wo = (const float*)d_in[8];
    const float* bo = (const float*)d_in[9];

    float* out   = (float*)d_out;                        // [4096, 512]
    float* attnf = out + (size_t)ROWS * DIMD;            // [32,1024,1024] fp32 probs
    float* dcl   = attnf + (size_t)BH * NTOK * NTOK;     // scalar

    // ws layout (bf16 regions first, all 16B-aligned); ~27 MB total
    char* wsb = (char*)d_ws;
    bf16_t* xb    = (bf16_t*)wsb;                              // 4 MB
    bf16_t* wt    = xb + (size_t)ROWS * DIMD;                  // 2 MB (4x 512x512)
    bf16_t* qb    = wt + (size_t)4 * DIMD * INNER;             // 4 MB
    bf16_t* kb    = qb + (size_t)BH * NTOK * DH;               // 4 MB
    bf16_t* vt    = kb + (size_t)BH * NTOK * DH;               // 4 MB
    bf16_t* ctxb  = vt + (size_t)BH * NTOK * DH;               // 4 MB
    float*  iqn   = (float*)(ctxb + (size_t)ROWS * INNER);     // 128 KB
    float*  ikn   = iqn + BH * NTOK;                           // 128 KB
    float*  cl    = ikn + BH * NTOK;                           // 128 KB
    float*  rg    = cl + BH * NTOK;                            // 16 KB
    unsigned int* mpk = (unsigned int*)(rg + BB * NTOK);       // 4 MB packed mask

    dim3 blk(256);
    prep_kernel<<<dim3(4096), blk, 0, stream>>>(x, Wq, Wk, Wv, Wo, mask, xb, wt, mpk);
    qkv_gemm<<<dim3(4, 64, 3), blk, 0, stream>>>(xb, wt, bq, bk, bv, qb, kb, vt, iqn, ikn);
    attn_fused<<<dim3(16, 32), dim3(512), 0, stream>>>(qb, kb, vt, mpk, iqn, ikn, attnf, ctxb, cl, rg);
    out_gemm<<<dim3(4, 64), blk, 0, stream>>>(ctxb, wt, bo, out, cl, rg, dcl);
}